// Round 1
// baseline (339.191 us; speedup 1.0000x reference)
//
#include <hip/hip_runtime.h>
#include <hip/hip_bf16.h>

#define BATCH 8
#define CIN   128
#define HH    256
#define WW    256
#define OUTC  64
#define INCH  1152   // CIN*9
#define HW    (HH*WW)

typedef __attribute__((ext_vector_type(8))) short short8;
typedef __attribute__((ext_vector_type(4))) float f32x4;

__device__ __forceinline__ unsigned short bf16r(float f) {
    unsigned u = __builtin_bit_cast(unsigned, f);
    u += 0x7fffu + ((u >> 16) & 1u);
    return (unsigned short)(u >> 16);
}

// wmod[b][tap][o][c] = bf16(weight[o][c*9+tap] * style[b][c*9+tap])
__global__ void __launch_bounds__(256) wmod_kernel(const float* __restrict__ weight,
                                                   const float* __restrict__ style,
                                                   unsigned short* __restrict__ wmod) {
    int i = blockIdx.x * 256 + threadIdx.x;
    if (i >= BATCH * 9 * OUTC * CIN) return;
    int c    = i & (CIN - 1);
    int rest = i >> 7;
    int o    = rest & (OUTC - 1);
    int bt   = rest >> 6;          // b*9 + tap
    int tap  = bt % 9;
    int b    = bt / 9;
    int k    = c * 9 + tap;
    float v = weight[o * INCH + k] * style[b * INCH + k];
    wmod[i] = bf16r(v);
}

// Tile: 64 outputs x (8 rows x 32 cols) pixels per block. 4 waves, each 64x64.
// xs[s][cc]: s = r*34+col over 10x34 halo tile, cc = c within 64-chunk (pad 72).
// ws[o][cc]: per-tap modulated weights.
template <bool GW>
__global__ void __launch_bounds__(256, 2) conv_kernel(
    const float* __restrict__ x,
    const unsigned short* __restrict__ wmod,
    const float* __restrict__ weight,
    const float* __restrict__ style,
    float* __restrict__ out)
{
    __shared__ __align__(16) unsigned short xs_sm[340 * 72];
    __shared__ __align__(16) unsigned short ws_sm[64 * 72];

    const int tid = threadIdx.x;
    const int bx  = blockIdx.x;            // 0..255 spatial tile
    const int b   = blockIdx.y;            // batch
    const int h0  = (bx >> 3) * 8;
    const int w0  = (bx & 7) * 32;

    // ---- staging geometry (j0 for all threads, j1 for tid < 84)
    const int j0 = tid, j1 = tid + 256;
    const int r0 = j0 / 34, cw0 = j0 % 34;
    const int r1 = j1 / 34, cw1 = j1 % 34;
    const int h_0 = h0 - 1 + r0, w_0 = w0 - 1 + cw0;
    const int h_1 = h0 - 1 + r1, w_1 = w0 - 1 + cw1;
    const bool ok0 = ((unsigned)h_0 < HH) & ((unsigned)w_0 < WW);
    const bool ok1 = (j1 < 340) && (((unsigned)h_1 < HH) & ((unsigned)w_1 < WW));
    const int off0 = h_0 * WW + w_0;
    const int off1 = h_1 * WW + w_1;

    // ---- compute geometry
    const int wv  = tid >> 6;
    const int l15 = tid & 15;
    const int kg  = (tid >> 4) & 3;

    int abase[4], prow[4], pcol[4];
#pragma unroll
    for (int mi = 0; mi < 4; ++mi) abase[mi] = (mi * 16 + l15) * 72 + kg * 8;
#pragma unroll
    for (int ni = 0; ni < 4; ++ni) {
        int p = wv * 64 + ni * 16 + l15;
        prow[ni] = p >> 5;
        pcol[ni] = p & 31;
    }

    f32x4 acc[4][4];
#pragma unroll
    for (int mi = 0; mi < 4; ++mi)
#pragma unroll
        for (int ni = 0; ni < 4; ++ni) acc[mi][ni] = (f32x4){0.f, 0.f, 0.f, 0.f};

    for (int chunk = 0; chunk < 2; ++chunk) {
        // ---- stage x chunk: c in [chunk*64, chunk*64+64)
        const float* xb = x + ((size_t)(b * CIN + chunk * 64)) * HW;
#pragma unroll 8
        for (int c2 = 0; c2 < 32; ++c2) {
            const float* xc = xb + (size_t)(2 * c2) * HW;
            float f0 = ok0 ? xc[off0] : 0.f;
            float f1 = ok0 ? xc[HW + off0] : 0.f;
            unsigned pk = (unsigned)bf16r(f0) | ((unsigned)bf16r(f1) << 16);
            *(unsigned*)&xs_sm[j0 * 72 + 2 * c2] = pk;
            if (j1 < 340) {
                float g0 = ok1 ? xc[off1] : 0.f;
                float g1 = ok1 ? xc[HW + off1] : 0.f;
                unsigned pk1 = (unsigned)bf16r(g0) | ((unsigned)bf16r(g1) << 16);
                *(unsigned*)&xs_sm[j1 * 72 + 2 * c2] = pk1;
            }
        }

        for (int tap = 0; tap < 9; ++tap) {
            const int kh = tap / 3, kw = tap % 3;
            // ---- stage per-tap weights
            if (GW) {
                const unsigned short* wm =
                    wmod + ((size_t)((b * 9 + tap) * OUTC)) * CIN + chunk * 64;
#pragma unroll
                for (int i2 = 0; i2 < 2; ++i2) {
                    int i  = tid + i2 * 256;
                    int o  = i >> 3, c8 = i & 7;
                    short8 v = *(const short8*)(wm + o * CIN + c8 * 8);
                    *(short8*)&ws_sm[o * 72 + c8 * 8] = v;
                }
            } else {
                for (int i = tid; i < 4096; i += 256) {
                    int o = i >> 6, cc = i & 63;
                    int k = (chunk * 64 + cc) * 9 + tap;
                    ws_sm[o * 72 + cc] = bf16r(weight[o * INCH + k] * style[b * INCH + k]);
                }
            }
            __syncthreads();

            // ---- 16 MFMA per k-half, accumulate across taps/chunks
            int bb[4];
#pragma unroll
            for (int ni = 0; ni < 4; ++ni)
                bb[ni] = ((prow[ni] + kh) * 34 + pcol[ni] + kw) * 72 + kg * 8;
#pragma unroll
            for (int kt = 0; kt < 2; ++kt) {
                short8 a[4], bv[4];
#pragma unroll
                for (int mi = 0; mi < 4; ++mi)
                    a[mi] = *(const short8*)&ws_sm[abase[mi] + kt * 32];
#pragma unroll
                for (int ni = 0; ni < 4; ++ni)
                    bv[ni] = *(const short8*)&xs_sm[bb[ni] + kt * 32];
#pragma unroll
                for (int mi = 0; mi < 4; ++mi)
#pragma unroll
                    for (int ni = 0; ni < 4; ++ni)
                        acc[mi][ni] = __builtin_amdgcn_mfma_f32_16x16x32_bf16(
                            a[mi], bv[ni], acc[mi][ni], 0, 0, 0);
            }
            __syncthreads();
        }
    }

    // ---- epilogue: D mapping col=lane&15 (pixel), row=(lane>>4)*4+r (o)
    float* op = out + ((size_t)b * OUTC) * HW;
#pragma unroll
    for (int mi = 0; mi < 4; ++mi) {
#pragma unroll
        for (int ni = 0; ni < 4; ++ni) {
            int p = wv * 64 + ni * 16 + l15;
            int h = h0 + (p >> 5), w = w0 + (p & 31);
#pragma unroll
            for (int r = 0; r < 4; ++r) {
                int o = mi * 16 + kg * 4 + r;
                op[(size_t)o * HW + h * WW + w] = acc[mi][ni][r];
            }
        }
    }
}

extern "C" void kernel_launch(void* const* d_in, const int* in_sizes, int n_in,
                              void* d_out, int out_size, void* d_ws, size_t ws_size,
                              hipStream_t stream) {
    const float* x      = (const float*)d_in[0];
    const float* style  = (const float*)d_in[1];
    const float* weight = (const float*)d_in[2];
    float* out = (float*)d_out;

    const size_t wmod_bytes = (size_t)BATCH * 9 * OUTC * CIN * sizeof(unsigned short);
    if (ws_size >= wmod_bytes) {
        int total = BATCH * 9 * OUTC * CIN;
        wmod_kernel<<<(total + 255) / 256, 256, 0, stream>>>(weight, style,
                                                             (unsigned short*)d_ws);
        conv_kernel<true><<<dim3(256, BATCH), 256, 0, stream>>>(
            x, (const unsigned short*)d_ws, nullptr, nullptr, out);
    } else {
        conv_kernel<false><<<dim3(256, BATCH), 256, 0, stream>>>(
            x, nullptr, weight, style, out);
    }
}

// Round 2
// 261.959 us; speedup vs baseline: 1.2948x; 1.2948x over previous
//
#include <hip/hip_runtime.h>
#include <hip/hip_bf16.h>

#define BATCH 8
#define CIN   128
#define HH    256
#define WW    256
#define OUTC  64
#define INCH  1152   // CIN*9
#define HW    (HH*WW)

typedef __attribute__((ext_vector_type(8))) short short8;
typedef __attribute__((ext_vector_type(4))) float f32x4;

__device__ __forceinline__ unsigned short bf16r(float f) {
    unsigned u = __builtin_bit_cast(unsigned, f);
    u += 0x7fffu + ((u >> 16) & 1u);
    return (unsigned short)(u >> 16);
}

// wmod[b][tap][o][c] = bf16(weight[o][c*9+tap] * style[b][c*9+tap])
__global__ void __launch_bounds__(256) wmod_kernel(const float* __restrict__ weight,
                                                   const float* __restrict__ style,
                                                   unsigned short* __restrict__ wmod) {
    int i = blockIdx.x * 256 + threadIdx.x;
    if (i >= BATCH * 9 * OUTC * CIN) return;
    int c    = i & (CIN - 1);
    int rest = i >> 7;
    int o    = rest & (OUTC - 1);
    int bt   = rest >> 6;          // b*9 + tap
    int tap  = bt % 9;
    int b    = bt / 9;
    int k    = c * 9 + tap;
    float v = weight[o * INCH + k] * style[b * INCH + k];
    wmod[i] = bf16r(v);
}

// Block: 64 outputs x (8 rows x 32 cols) pixels. 4 waves, each 64 o x 64 px.
// xs[s][c]: s = r*34+col over 10x34 halo, c = channel within 64-chunk (pad 72
// shorts = 36 dwords -> lane stride 4 mod 32 banks: 2-way on b128, free).
// Weights: per-tap A-fragments loaded straight from wmod (L2-hot), no LDS,
// no per-tap barrier. 2 barriers per chunk, 4 total.
template <bool GW>
__global__ void __launch_bounds__(256, 3) conv_kernel(
    const float* __restrict__ x,
    const unsigned short* __restrict__ wmod,
    const float* __restrict__ weight,
    const float* __restrict__ style,
    float* __restrict__ out)
{
    __shared__ __align__(16) unsigned short xs_sm[340 * 72];

    const int tid = threadIdx.x;
    const int bx  = blockIdx.x;            // 0..255 spatial tile
    const int b   = blockIdx.y;            // batch
    const int h0  = (bx >> 3) * 8;
    const int w0  = (bx & 7) * 32;

    const int wv  = tid >> 6;
    const int l15 = tid & 15;
    const int kg  = (tid >> 4) & 3;

    int prow[4], pcol[4];
#pragma unroll
    for (int ni = 0; ni < 4; ++ni) {
        int p = wv * 64 + ni * 16 + l15;
        prow[ni] = p >> 5;
        pcol[ni] = p & 31;
    }

    f32x4 acc[4][4];
#pragma unroll
    for (int mi = 0; mi < 4; ++mi)
#pragma unroll
        for (int ni = 0; ni < 4; ++ni) acc[mi][ni] = (f32x4){0.f, 0.f, 0.f, 0.f};

    for (int chunk = 0; chunk < 2; ++chunk) {
        __syncthreads();   // chunk>0: protect xs from previous chunk's readers

        // ---- stage x chunk: tasks t = (cg 0..7, s 0..339); consecutive lanes
        // -> consecutive pixels s -> coalesced global loads, conflict-free
        // ds_write_b128 (lane dword-stride 36 == 4 mod 32).
        const float* xb = x + ((size_t)(b * CIN + chunk * 64)) * HW;
        for (int t = tid; t < 2720; t += 256) {
            int cg  = t / 340;
            int s   = t - cg * 340;
            int r   = s / 34;
            int col = s - r * 34;
            int h = h0 - 1 + r, w = w0 - 1 + col;
            bool ok = ((unsigned)h < HH) && ((unsigned)w < WW);
            int off = h * WW + w;
            const float* xc = xb + (size_t)(cg * 8) * HW;
            short8 sv;
#pragma unroll
            for (int j = 0; j < 8; ++j) {
                float f = ok ? xc[(size_t)j * HW + off] : 0.f;
                sv[j] = (short)bf16r(f);
            }
            *(short8*)&xs_sm[s * 72 + cg * 8] = sv;
        }
        __syncthreads();

        // ---- 9 taps, A from global (registers), B from LDS, 288 MFMA/wave
        const unsigned short* wmb = wmod + ((size_t)(b * 9) * OUTC) * CIN + chunk * 64;
#pragma unroll
        for (int tap = 0; tap < 9; ++tap) {
            const int kh = tap / 3, kw = tap % 3;

            short8 A[4][2];
            if (GW) {
                const unsigned short* wt = wmb + (size_t)tap * OUTC * CIN;
#pragma unroll
                for (int mi = 0; mi < 4; ++mi)
#pragma unroll
                    for (int kt = 0; kt < 2; ++kt)
                        A[mi][kt] = *(const short8*)(wt + (mi * 16 + l15) * CIN +
                                                     kt * 32 + kg * 8);
            } else {
#pragma unroll
                for (int mi = 0; mi < 4; ++mi)
#pragma unroll
                    for (int kt = 0; kt < 2; ++kt) {
                        int o = mi * 16 + l15;
#pragma unroll
                        for (int j = 0; j < 8; ++j) {
                            int c = chunk * 64 + kt * 32 + kg * 8 + j;
                            int k = c * 9 + tap;
                            A[mi][kt][j] = (short)bf16r(weight[o * INCH + k] *
                                                        style[b * INCH + k]);
                        }
                    }
            }

            int bb[4];
#pragma unroll
            for (int ni = 0; ni < 4; ++ni)
                bb[ni] = ((prow[ni] + kh) * 34 + pcol[ni] + kw) * 72 + kg * 8;

#pragma unroll
            for (int kt = 0; kt < 2; ++kt) {
                short8 Bv[4];
#pragma unroll
                for (int ni = 0; ni < 4; ++ni)
                    Bv[ni] = *(const short8*)&xs_sm[bb[ni] + kt * 32];
#pragma unroll
                for (int mi = 0; mi < 4; ++mi)
#pragma unroll
                    for (int ni = 0; ni < 4; ++ni)
                        acc[mi][ni] = __builtin_amdgcn_mfma_f32_16x16x32_bf16(
                            A[mi][kt], Bv[ni], acc[mi][ni], 0, 0, 0);
            }
        }
    }

    // ---- epilogue: D mapping col=lane&15 (pixel), row=(lane>>4)*4+r (o)
    float* op = out + ((size_t)b * OUTC) * HW;
#pragma unroll
    for (int mi = 0; mi < 4; ++mi) {
#pragma unroll
        for (int ni = 0; ni < 4; ++ni) {
            int p = wv * 64 + ni * 16 + l15;
            int h = h0 + (p >> 5), w = w0 + (p & 31);
#pragma unroll
            for (int r = 0; r < 4; ++r) {
                int o = mi * 16 + kg * 4 + r;
                op[(size_t)o * HW + h * WW + w] = acc[mi][ni][r];
            }
        }
    }
}

extern "C" void kernel_launch(void* const* d_in, const int* in_sizes, int n_in,
                              void* d_out, int out_size, void* d_ws, size_t ws_size,
                              hipStream_t stream) {
    const float* x      = (const float*)d_in[0];
    const float* style  = (const float*)d_in[1];
    const float* weight = (const float*)d_in[2];
    float* out = (float*)d_out;

    const size_t wmod_bytes = (size_t)BATCH * 9 * OUTC * CIN * sizeof(unsigned short);
    if (ws_size >= wmod_bytes) {
        int total = BATCH * 9 * OUTC * CIN;
        wmod_kernel<<<(total + 255) / 256, 256, 0, stream>>>(weight, style,
                                                             (unsigned short*)d_ws);
        conv_kernel<true><<<dim3(256, BATCH), 256, 0, stream>>>(
            x, (const unsigned short*)d_ws, nullptr, nullptr, out);
    } else {
        conv_kernel<false><<<dim3(256, BATCH), 256, 0, stream>>>(
            x, nullptr, weight, style, out);
    }
}

// Round 3
// 248.653 us; speedup vs baseline: 1.3641x; 1.0535x over previous
//
#include <hip/hip_runtime.h>
#include <hip/hip_bf16.h>

#define BATCH 8
#define CIN   128
#define HH    256
#define WW    256
#define OUTC  64
#define INCH  1152   // CIN*9
#define HW    (HH*WW)

typedef __attribute__((ext_vector_type(8))) short short8;
typedef __attribute__((ext_vector_type(4))) float f32x4;

__device__ __forceinline__ unsigned short bf16r(float f) {
    unsigned u = __builtin_bit_cast(unsigned, f);
    u += 0x7fffu + ((u >> 16) & 1u);
    return (unsigned short)(u >> 16);
}

// wmod[b][tap][o][c] = bf16(weight[o][c*9+tap] * style[b][c*9+tap])
__global__ void __launch_bounds__(256) wmod_kernel(const float* __restrict__ weight,
                                                   const float* __restrict__ style,
                                                   unsigned short* __restrict__ wmod) {
    int i = blockIdx.x * 256 + threadIdx.x;
    if (i >= BATCH * 9 * OUTC * CIN) return;
    int c    = i & (CIN - 1);
    int rest = i >> 7;
    int o    = rest & (OUTC - 1);
    int bt   = rest >> 6;          // b*9 + tap
    int tap  = bt % 9;
    int b    = bt / 9;
    int k    = c * 9 + tap;
    float v = weight[o * INCH + k] * style[b * INCH + k];
    wmod[i] = bf16r(v);
}

// Block: 64 outputs x (8 rows x 32 cols) pixels. 4 waves, each 64 o x 64 px.
// Channel chunk = 32 (full MFMA K). LDS: paired pixel-rows, 128B/row:
//   addr(s,c) = (s>>1)*64 + (((((s&1)<<2)|(c>>3)) ^ ((s>>1)&7))*8 + (c&7)
// XOR granule swizzle -> 2-way max on both ds_write_b128 and ds_read_b128.
// 21.25 KB LDS -> 4 blocks/CU with VGPR<=128.
template <bool GW>
__global__ void __launch_bounds__(256, 4) conv_kernel(
    const float* __restrict__ x,
    const unsigned short* __restrict__ wmod,
    const float* __restrict__ weight,
    const float* __restrict__ style,
    float* __restrict__ out)
{
    __shared__ __align__(16) unsigned short xs_sm[170 * 64];

    const int tid = threadIdx.x;
    const int bx  = blockIdx.x;            // 0..255 spatial tile
    const int b   = blockIdx.y;            // batch
    const int h0  = (bx >> 3) * 8;
    const int w0  = (bx & 7) * 32;

    const int wv  = tid >> 6;
    const int l15 = tid & 15;
    const int kg  = (tid >> 4) & 3;

    int prow[4], pcol[4];
#pragma unroll
    for (int ni = 0; ni < 4; ++ni) {
        int p = wv * 64 + ni * 16 + l15;
        prow[ni] = p >> 5;
        pcol[ni] = p & 31;
    }

    f32x4 acc[4][4];
#pragma unroll
    for (int mi = 0; mi < 4; ++mi)
#pragma unroll
        for (int ni = 0; ni < 4; ++ni) acc[mi][ni] = (f32x4){0.f, 0.f, 0.f, 0.f};

    for (int chunk = 0; chunk < 4; ++chunk) {
        if (chunk) __syncthreads();        // protect xs from previous readers

        // ---- stage x chunk (32 channels): tasks t = (cg 0..3, s 0..339)
        const float* xb = x + ((size_t)(b * CIN + chunk * 32)) * HW;
        for (int t = tid; t < 1360; t += 256) {
            int cg  = t / 340;
            int s   = t - cg * 340;
            int r   = s / 34;
            int col = s - r * 34;
            int h = h0 - 1 + r, w = w0 - 1 + col;
            bool ok = ((unsigned)h < HH) && ((unsigned)w < WW);
            int off = h * WW + w;
            const float* xc = xb + (size_t)(cg * 8) * HW;
            short8 sv;
#pragma unroll
            for (int j = 0; j < 8; ++j) {
                float f = ok ? xc[(size_t)j * HW + off] : 0.f;
                sv[j] = (short)bf16r(f);
            }
            int q = s >> 1;
            int g = (((s & 1) << 2) | cg) ^ (q & 7);
            *(short8*)&xs_sm[q * 64 + g * 8] = sv;
        }
        __syncthreads();

        // ---- 9 taps: A from wmod (L2-hot) into regs, B from swizzled LDS
        const unsigned short* wmb = wmod + ((size_t)(b * 9) * OUTC) * CIN + chunk * 32;
#pragma unroll
        for (int tap = 0; tap < 9; ++tap) {
            const int kh = tap / 3, kw = tap % 3;

            short8 A[4];
            if (GW) {
                const unsigned short* wt = wmb + (size_t)tap * OUTC * CIN;
#pragma unroll
                for (int mi = 0; mi < 4; ++mi)
                    A[mi] = *(const short8*)(wt + (mi * 16 + l15) * CIN + kg * 8);
            } else {
#pragma unroll
                for (int mi = 0; mi < 4; ++mi) {
                    int o = mi * 16 + l15;
#pragma unroll
                    for (int j = 0; j < 8; ++j) {
                        int c = chunk * 32 + kg * 8 + j;
                        int k = c * 9 + tap;
                        A[mi][j] = (short)bf16r(weight[o * INCH + k] *
                                                style[b * INCH + k]);
                    }
                }
            }

            short8 Bv[4];
#pragma unroll
            for (int ni = 0; ni < 4; ++ni) {
                int s = (prow[ni] + kh) * 34 + pcol[ni] + kw;
                int q = s >> 1;
                int g = (((s & 1) << 2) | kg) ^ (q & 7);
                Bv[ni] = *(const short8*)&xs_sm[q * 64 + g * 8];
            }
#pragma unroll
            for (int mi = 0; mi < 4; ++mi)
#pragma unroll
                for (int ni = 0; ni < 4; ++ni)
                    acc[mi][ni] = __builtin_amdgcn_mfma_f32_16x16x32_bf16(
                        A[mi], Bv[ni], acc[mi][ni], 0, 0, 0);
        }
    }

    // ---- epilogue: D mapping col=lane&15 (pixel), row=(lane>>4)*4+r (o)
    float* op = out + ((size_t)b * OUTC) * HW;
#pragma unroll
    for (int mi = 0; mi < 4; ++mi) {
#pragma unroll
        for (int ni = 0; ni < 4; ++ni) {
            int p = wv * 64 + ni * 16 + l15;
            int h = h0 + (p >> 5), w = w0 + (p & 31);
#pragma unroll
            for (int r = 0; r < 4; ++r) {
                int o = mi * 16 + kg * 4 + r;
                op[(size_t)o * HW + h * WW + w] = acc[mi][ni][r];
            }
        }
    }
}

extern "C" void kernel_launch(void* const* d_in, const int* in_sizes, int n_in,
                              void* d_out, int out_size, void* d_ws, size_t ws_size,
                              hipStream_t stream) {
    const float* x      = (const float*)d_in[0];
    const float* style  = (const float*)d_in[1];
    const float* weight = (const float*)d_in[2];
    float* out = (float*)d_out;

    const size_t wmod_bytes = (size_t)BATCH * 9 * OUTC * CIN * sizeof(unsigned short);
    if (ws_size >= wmod_bytes) {
        int total = BATCH * 9 * OUTC * CIN;
        wmod_kernel<<<(total + 255) / 256, 256, 0, stream>>>(weight, style,
                                                             (unsigned short*)d_ws);
        conv_kernel<true><<<dim3(256, BATCH), 256, 0, stream>>>(
            x, (const unsigned short*)d_ws, nullptr, nullptr, out);
    } else {
        conv_kernel<false><<<dim3(256, BATCH), 256, 0, stream>>>(
            x, nullptr, weight, style, out);
    }
}